// Round 6
// baseline (347.386 us; speedup 1.0000x reference)
//
#include <hip/hip_runtime.h>

// Shift-TCN fused pipeline v7, MI355X (gfx950).
// ht layout CHANGED to [c][j]  (j = n*1600+tv contiguous).
// [memset acc=0]
// [K12] pure streaming (no LDS): per (n,c) row, 5 aligned f4 loads -> BN1 stats
//       + shift_raw lerp in regs -> ht2[c][j] bf16, fully coalesced
// [Kp ] params: W'b = bf16(W*sc), b2all/S0/S63 rank corrections
// [K3 ] MFMA GEMM o=256, j=128, K=32, 3-buf vmcnt(6) pipeline (v6 schedule);
//       B staged from ht2[c][j] via gload_lds into subtiled [K4][J16][4][16] LDS,
//       B-fragments via ds_read_b64_tr_b16 (HW transpose); A-path = v6 (swizzled)
// [K4 ] BN2 analytic stats streaming (v6)
// [K5 ] shift_out + BN2 affine div-free (v6)

#define EPSV 1e-5f
constexpr int Nn = 64, Cc = 256, Tt = 64, Vv = 25;
constexpr int TV = Tt * Vv;          // 1600
constexpr int CTV = Cc * TV;         // 409600
constexpr int NJ = Nn * TV;          // 102400 (j extent)
constexpr float Minv = 1.0f / (Nn * TV);   // 1/102400

typedef short short8 __attribute__((ext_vector_type(8)));
typedef float floatx4 __attribute__((ext_vector_type(4)));
typedef unsigned int uintx2 __attribute__((ext_vector_type(2)));
typedef unsigned int uintx4 __attribute__((ext_vector_type(4)));

__device__ __forceinline__ unsigned short f2bf(float f) {
    unsigned int u = __builtin_bit_cast(unsigned int, f);
    u += 0x7FFFu + ((u >> 16) & 1u);      // round-to-nearest-even
    return (unsigned short)(u >> 16);
}
__device__ __forceinline__ float bflo(unsigned int w) {
    return __builtin_bit_cast(float, w << 16);
}
__device__ __forceinline__ float bfhi(unsigned int w) {
    return __builtin_bit_cast(float, w & 0xFFFF0000u);
}
__device__ __forceinline__ void unp8v(uint4 u, float* o) {
    o[0] = bflo(u.x); o[1] = bfhi(u.x); o[2] = bflo(u.y); o[3] = bfhi(u.y);
    o[4] = bflo(u.z); o[5] = bfhi(u.z); o[6] = bflo(u.w); o[7] = bfhi(u.w);
}
__device__ __forceinline__ void gload_lds16(const void* g, void* l) {
    __builtin_amdgcn_global_load_lds((const __attribute__((address_space(1))) void*)g,
                                     (__attribute__((address_space(3))) void*)l, 16, 0, 0);
}

// ------- K12: streaming BN1 stats + shift_raw -> ht2[c][j]. grid (64 n, 256 c) -------
__global__ __launch_bounds__(256) void k_bn1_stream(const float* __restrict__ x,
                                                    const float* __restrict__ theta,
                                                    float* __restrict__ sacc,
                                                    float* __restrict__ qacc,
                                                    unsigned short* __restrict__ ht2) {
    int n = blockIdx.x, c = blockIdx.y, tid = threadIdx.x;
    const float* xr = x + (size_t)n * CTV + (size_t)c * TV;
    float th = theta[c];
    float fd = floorf(th);
    int d = (int)fd;                 // in {-1, 0}
    float f = th - fd, omf = 1.f - f;
    float s = 0.f, q = 0.f;
    if (tid < 200) {
        int e = tid * 8;
        float4 m0 = *(const float4*)(xr + e);
        float4 m1 = *(const float4*)(xr + e + 4);
        float M[8] = {m0.x, m0.y, m0.z, m0.w, m1.x, m1.y, m1.z, m1.w};
#pragma unroll
        for (int k = 0; k < 8; ++k) { s += M[k]; q += M[k] * M[k]; }
        float out[8];
        if (d < 0) {                 // needs x[e+k-25], valid iff e+k>=25
            int b0 = e - 28; if (b0 < 0) b0 = 0;
            int b1 = e - 24; if (b1 < 0) b1 = 0;
            int b2 = e - 20; if (b2 < 0) b2 = 0;
            float4 l0 = *(const float4*)(xr + b0);
            float4 l1 = *(const float4*)(xr + b1);
            float4 l2 = *(const float4*)(xr + b2);
            float S[8] = { l0.w, l1.x, l1.y, l1.z, l1.w, l2.x, l2.y, l2.z };
#pragma unroll
            for (int k = 0; k < 8; ++k) {
                float v0 = (e + k >= 25) ? S[k] : 0.f;
                out[k] = omf * v0 + f * M[k];
            }
        } else {                     // needs x[e+k+25], valid iff e+k<1575
            int b0 = e + 24; if (b0 > 1596) b0 = 1596;
            int b1 = e + 28; if (b1 > 1596) b1 = 1596;
            int b2 = e + 32; if (b2 > 1596) b2 = 1596;
            float4 l0 = *(const float4*)(xr + b0);
            float4 l1 = *(const float4*)(xr + b1);
            float4 l2 = *(const float4*)(xr + b2);
            float S[8] = { l0.y, l0.z, l0.w, l1.x, l1.y, l1.z, l1.w, l2.x };
#pragma unroll
            for (int k = 0; k < 8; ++k) {
                float v1 = (e + k < 1575) ? S[k] : 0.f;
                out[k] = omf * M[k] + f * v1;
            }
        }
        unsigned int w4[4];
#pragma unroll
        for (int k = 0; k < 8; k += 2)
            w4[k >> 1] = (unsigned)f2bf(out[k]) | (((unsigned)f2bf(out[k + 1])) << 16);
        uint4 st = { w4[0], w4[1], w4[2], w4[3] };
        *(uint4*)(ht2 + (size_t)c * NJ + n * TV + e) = st;
    }
    for (int off = 32; off; off >>= 1) { s += __shfl_down(s, off); q += __shfl_down(q, off); }
    __shared__ float red[8];
    int wv = tid >> 6;
    if ((tid & 63) == 0) { red[wv] = s; red[4 + wv] = q; }
    __syncthreads();
    if (tid == 0) {
        atomicAdd(&sacc[c], red[0] + red[1] + red[2] + red[3]);
        atomicAdd(&qacc[c], red[4] + red[5] + red[6] + red[7]);
    }
}

// ------- Kp: finalize BN1 params; W'b = bf16(W*sc); rank-corrections -------
__global__ __launch_bounds__(256) void k_params(const float* __restrict__ w,
                                                const float* __restrict__ bias,
                                                const float* __restrict__ sacc,
                                                const float* __restrict__ qacc,
                                                const float* __restrict__ g,
                                                const float* __restrict__ b,
                                                const float* __restrict__ theta,
                                                unsigned short* __restrict__ wb,
                                                float* __restrict__ b2all,
                                                float* __restrict__ s0v,
                                                float* __restrict__ s63v) {
    int o = blockIdx.x, c = threadIdx.x;
    float mean = sacc[c] * Minv;
    float var  = qacc[c] * Minv - mean * mean;
    float sc = g[c] * rsqrtf(var + EPSV);
    float tc = b[c] - mean * sc;
    float th = theta[c];
    float fd = floorf(th);
    int d = (int)fd;
    float f = th - fd;
    float wv = w[o * 256 + c];
    wb[o * 256 + c] = f2bf(wv * sc);
    float wtc = wv * tc;
    float r0  = (d < 0) ? wtc * (1.f - f) : 0.f;   // t==0 correction (d==-1)
    float r63 = (d == 0) ? wtc * f : 0.f;          // t==63 correction (d==0)
    for (int off = 32; off; off >>= 1) {
        wtc += __shfl_down(wtc, off);
        r0  += __shfl_down(r0, off);
        r63 += __shfl_down(r63, off);
    }
    __shared__ float aux[3][4];
    if ((c & 63) == 0) { int wi = c >> 6; aux[0][wi] = wtc; aux[1][wi] = r0; aux[2][wi] = r63; }
    __syncthreads();
    if (c == 0) {
        b2all[o] = bias[o] + aux[0][0] + aux[0][1] + aux[0][2] + aux[0][3];
        s0v[o]  = aux[1][0] + aux[1][1] + aux[1][2] + aux[1][3];
        s63v[o] = aux[2][0] + aux[2][1] + aux[2][2] + aux[2][3];
    }
}

// ------- K3: y = relu(W' ht + bias2). o=256, j=128, K=32, 3-buf + tr_b16 B -------
// LDS per buf 24KB: A[256][32] (16KB, XOR-swizzled) + B subtiled [K4=8][J16=8][4][16] (8KB).
__global__ __launch_bounds__(256, 2) void k_gemm(const unsigned short* __restrict__ ht2,
                                                 const unsigned short* __restrict__ wb,
                                                 const float* __restrict__ b2all,
                                                 const float* __restrict__ s0v,
                                                 const float* __restrict__ s63v,
                                                 unsigned short* __restrict__ y) {
    int j0 = blockIdx.x * 128;
    int tid = threadIdx.x;
    int w = tid >> 6, lane = tid & 63;
    int quad = lane >> 4, l16 = lane & 15;
    __shared__ __attribute__((aligned(16))) unsigned short smem[36864]; // 73,728 B (3 bufs)
    floatx4 acc[4][8] = {};
    // A staging (v6): pre-swizzled source granule, linear LDS dest.
    int sg = (lane & 3) ^ ((lane >> 3) & 3);
    const unsigned short* wpA = wb + (size_t)(w * 64 + (lane >> 2)) * 256 + sg * 8;
    int rg = quad ^ ((l16 >> 1) & 3);          // A fragment-read granule
    // B staging: lane l stages 16B of subtile st=(w*2+i)*8+(l>>3), row r=(l&7)>>1,
    // cols (l>>3)*16+(l&1)*8 from ht2 row (K4*4+r) -- source pre-permuted so that
    // linear gload_lds writes produce the subtiled [4][16] layout.
    int brow0 = w * 8 + ((lane & 7) >> 1);                 // i=0 rows (K4=2w)
    int bcol  = (lane >> 3) * 16 + (lane & 1) * 8;
    const unsigned short* hp0 = ht2 + (size_t)brow0 * NJ + j0 + bcol;
    const unsigned short* hp1 = hp0 + (size_t)4 * NJ;      // i=1 (K4=2w+1)
    // B tr-read per-lane base: subtile (2*quad)*8, column l16
    unsigned trlane = (unsigned)(quad * 2048 + l16 * 8);

#define STAGE(buf, kt)                                                                  \
    {                                                                                   \
        unsigned short* Ab_ = smem + (buf) * 12288;                                     \
        unsigned short* Bb_ = Ab_ + 8192;                                               \
        _Pragma("unroll")                                                               \
        for (int a = 0; a < 4; ++a)                                                     \
            gload_lds16(wpA + (size_t)a * 16 * 256 + (kt) * 32, Ab_ + (w * 64 + a * 16) * 32); \
        gload_lds16(hp0 + (size_t)(kt) * (32 * (size_t)NJ), Bb_ + (w * 2) * 512);       \
        gload_lds16(hp1 + (size_t)(kt) * (32 * (size_t)NJ), Bb_ + (w * 2 + 1) * 512);   \
    }
#define COMPUTE(buf)                                                                    \
    {                                                                                   \
        const unsigned short* Ab_ = smem + (buf) * 12288;                               \
        unsigned ba = (unsigned)(size_t)(const void*)(Ab_ + 8192) + trlane;             \
        short8 af[4];                                                                   \
        _Pragma("unroll")                                                               \
        for (int m = 0; m < 4; ++m)                                                     \
            af[m] = *(const short8*)&Ab_[(w * 64 + m * 16 + l16) * 32 + rg * 8];        \
        uintx2 t0_, t1_, t2_, t3_, t4_, t5_, t6_, t7_;                                  \
        uintx2 u0_, u1_, u2_, u3_, u4_, u5_, u6_, u7_;                                  \
        asm volatile("ds_read_b64_tr_b16 %0, %2 offset:0\n\t"                           \
                     "ds_read_b64_tr_b16 %1, %2 offset:1024"                            \
                     : "=v"(t0_), "=v"(u0_) : "v"(ba));                                 \
        asm volatile("ds_read_b64_tr_b16 %0, %2 offset:0\n\t"                           \
                     "ds_read_b64_tr_b16 %1, %2 offset:1024"                            \
                     : "=v"(t1_), "=v"(u1_) : "v"(ba + 128));                           \
        asm volatile("ds_read_b64_tr_b16 %0, %2 offset:0\n\t"                           \
                     "ds_read_b64_tr_b16 %1, %2 offset:1024"                            \
                     : "=v"(t2_), "=v"(u2_) : "v"(ba + 256));                           \
        asm volatile("ds_read_b64_tr_b16 %0, %2 offset:0\n\t"                           \
                     "ds_read_b64_tr_b16 %1, %2 offset:1024"                            \
                     : "=v"(t3_), "=v"(u3_) : "v"(ba + 384));                           \
        asm volatile("ds_read_b64_tr_b16 %0, %2 offset:0\n\t"                           \
                     "ds_read_b64_tr_b16 %1, %2 offset:1024"                            \
                     : "=v"(t4_), "=v"(u4_) : "v"(ba + 512));                           \
        asm volatile("ds_read_b64_tr_b16 %0, %2 offset:0\n\t"                           \
                     "ds_read_b64_tr_b16 %1, %2 offset:1024"                            \
                     : "=v"(t5_), "=v"(u5_) : "v"(ba + 640));                           \
        asm volatile("ds_read_b64_tr_b16 %0, %2 offset:0\n\t"                           \
                     "ds_read_b64_tr_b16 %1, %2 offset:1024"                            \
                     : "=v"(t6_), "=v"(u6_) : "v"(ba + 768));                           \
        asm volatile("ds_read_b64_tr_b16 %0, %2 offset:0\n\t"                           \
                     "ds_read_b64_tr_b16 %1, %2 offset:1024"                            \
                     : "=v"(t7_), "=v"(u7_) : "v"(ba + 896));                           \
        asm volatile("s_waitcnt lgkmcnt(0)" ::: "memory");                              \
        __builtin_amdgcn_sched_barrier(0);                                              \
        __builtin_amdgcn_s_setprio(1);                                                  \
        uintx4 uu;                                                                      \
        short8 bfr;                                                                     \
        _Pragma("unroll")                                                               \
        for (int m = 0; m < 4; ++m) {                                                   \
            uu = (uintx4){t0_.x, t0_.y, u0_.x, u0_.y}; bfr = __builtin_bit_cast(short8, uu); \
            acc[m][0] = __builtin_amdgcn_mfma_f32_16x16x32_bf16(af[m], bfr, acc[m][0], 0, 0, 0); \
            uu = (uintx4){t1_.x, t1_.y, u1_.x, u1_.y}; bfr = __builtin_bit_cast(short8, uu); \
            acc[m][1] = __builtin_amdgcn_mfma_f32_16x16x32_bf16(af[m], bfr, acc[m][1], 0, 0, 0); \
            uu = (uintx4){t2_.x, t2_.y, u2_.x, u2_.y}; bfr = __builtin_bit_cast(short8, uu); \
            acc[m][2] = __builtin_amdgcn_mfma_f32_16x16x32_bf16(af[m], bfr, acc[m][2], 0, 0, 0); \
            uu = (uintx4){t3_.x, t3_.y, u3_.x, u3_.y}; bfr = __builtin_bit_cast(short8, uu); \
            acc[m][3] = __builtin_amdgcn_mfma_f32_16x16x32_bf16(af[m], bfr, acc[m][3], 0, 0, 0); \
            uu = (uintx4){t4_.x, t4_.y, u4_.x, u4_.y}; bfr = __builtin_bit_cast(short8, uu); \
            acc[m][4] = __builtin_amdgcn_mfma_f32_16x16x32_bf16(af[m], bfr, acc[m][4], 0, 0, 0); \
            uu = (uintx4){t5_.x, t5_.y, u5_.x, u5_.y}; bfr = __builtin_bit_cast(short8, uu); \
            acc[m][5] = __builtin_amdgcn_mfma_f32_16x16x32_bf16(af[m], bfr, acc[m][5], 0, 0, 0); \
            uu = (uintx4){t6_.x, t6_.y, u6_.x, u6_.y}; bfr = __builtin_bit_cast(short8, uu); \
            acc[m][6] = __builtin_amdgcn_mfma_f32_16x16x32_bf16(af[m], bfr, acc[m][6], 0, 0, 0); \
            uu = (uintx4){t7_.x, t7_.y, u7_.x, u7_.y}; bfr = __builtin_bit_cast(short8, uu); \
            acc[m][7] = __builtin_amdgcn_mfma_f32_16x16x32_bf16(af[m], bfr, acc[m][7], 0, 0, 0); \
        }                                                                               \
        __builtin_amdgcn_s_setprio(0);                                                  \
    }
#define WAITVM(n) asm volatile("s_waitcnt vmcnt(" #n ")" ::: "memory")
#define BAR() __builtin_amdgcn_s_barrier()

    STAGE(0, 0)           // 6 in flight / wave
    STAGE(1, 1)           // 12 in flight
    WAITVM(6); BAR();     // buf0 landed
    STAGE(2, 2)
    COMPUTE(0)
    WAITVM(6); BAR();     // buf1 landed
    STAGE(0, 3)
    COMPUTE(1)
    WAITVM(6); BAR();
    STAGE(1, 4)
    COMPUTE(2)
    WAITVM(6); BAR();
    STAGE(2, 5)
    COMPUTE(0)
    WAITVM(6); BAR();
    STAGE(0, 6)
    COMPUTE(1)
    WAITVM(6); BAR();
    STAGE(1, 7)
    COMPUTE(2)
    WAITVM(6); BAR();     // buf0 (kt6) landed
    COMPUTE(0)
    WAITVM(0); BAR();     // final drain (kt7)
    COMPUTE(1)
#undef STAGE
#undef COMPUTE
#undef WAITVM
#undef BAR

    __syncthreads();                       // compute done before smem reuse
    unsigned short* Cl = smem;             // [128 o][136 pad] bf16 (34,816 B)
    int li = tid & 15, orow = tid >> 4;
#pragma unroll
    for (int p = 0; p < 2; ++p) {
        if ((w >> 1) == p) {
            int rowbase = (w & 1) * 64;
#pragma unroll
            for (int m = 0; m < 4; ++m) {
                int ob = p * 128 + (w & 1) * 64 + m * 16 + quad * 4;
#pragma unroll
                for (int r = 0; r < 4; ++r) {
                    int o = ob + r;
                    float bb = b2all[o], e0 = s0v[o], e63 = s63v[o];
                    int lrow = rowbase + m * 16 + quad * 4 + r;
#pragma unroll
                    for (int jt = 0; jt < 8; ++jt) {
                        int jj = j0 + jt * 16;
                        int nn = jj / 1600;
                        int tvb = jj - nn * 1600 + l16;
                        float bia = bb - (tvb < 25 ? e0 : 0.f) - (tvb >= 1575 ? e63 : 0.f);
                        float v = acc[m][jt][r] + bia;
                        v = v > 0.f ? v : 0.f;
                        Cl[lrow * 136 + jt * 16 + l16] = f2bf(v);
                    }
                }
            }
        }
        __syncthreads();
#pragma unroll
        for (int pass = 0; pass < 8; ++pass) {
            int ol = orow + pass * 16;
            uint4 vv = *(const uint4*)&Cl[ol * 136 + li * 8];
            int o = p * 128 + ol;
            int j = j0 + li * 8;
            int nn = j / 1600;
            int tv = j - nn * 1600;
            *(uint4*)(y + (size_t)nn * CTV + (size_t)o * TV + tv) = vv;
        }
        if (p == 0) __syncthreads();
    }
}

// ------- K4: BN2 analytic partial sums over y (no gather). grid (8 ngrp, 256 o) -------
__global__ __launch_bounds__(256) void k_bn2_stats(const unsigned short* __restrict__ y,
                                                   float* __restrict__ acc7) {
    int o = blockIdx.y, ng = blockIdx.x, tid = threadIdx.x;
    float S = 0.f, Q = 0.f, P = 0.f, Y0 = 0.f, Q0 = 0.f, Y63 = 0.f, Q63 = 0.f;
    if (tid < 200) {
        int e = tid * 8;
        int eB = e + 24; if (eB > 1592) eB = 1592;
        int eC = e + 32; if (eC > 1592) eC = 1592;
        const unsigned short* base0 = y + (size_t)(ng * 8) * CTV + (size_t)o * TV;
        uint4 ua = *(const uint4*)(base0 + e);
        uint4 ub = *(const uint4*)(base0 + eB);
        uint4 uc = *(const uint4*)(base0 + eC);
        for (int nn = 0; nn < 8; ++nn) {
            uint4 na, nb, nc;
            if (nn < 7) {
                const unsigned short* row = base0 + (size_t)(nn + 1) * CTV;
                na = *(const uint4*)(row + e);
                nb = *(const uint4*)(row + eB);
                nc = *(const uint4*)(row + eC);
            }
            float a[8], b[8], c[8];
            unp8v(ua, a); unp8v(ub, b); unp8v(uc, c);
#pragma unroll
            for (int k = 0; k < 8; ++k) {
                float v = a[k];
                S += v; Q += v * v;
                float vn = (k < 7) ? b[k + 1] : c[0];     // y[e+k+25]
                if (e + k < 1575) P += v * vn;
            }
            if (e < 32) {
#pragma unroll
                for (int k = 0; k < 8; ++k)
                    if (e + k < 25) { Y0 += a[k]; Q0 += a[k] * a[k]; }
            }
            if (e >= 1568) {
#pragma unroll
                for (int k = 0; k < 8; ++k)
                    if (e + k >= 1575) { Y63 += a[k]; Q63 += a[k] * a[k]; }
            }
            ua = na; ub = nb; uc = nc;
        }
    }
    for (int off = 32; off; off >>= 1) {
        S += __shfl_down(S, off); Q += __shfl_down(Q, off); P += __shfl_down(P, off);
        Y0 += __shfl_down(Y0, off); Q0 += __shfl_down(Q0, off);
        Y63 += __shfl_down(Y63, off); Q63 += __shfl_down(Q63, off);
    }
    if ((tid & 63) == 0) {
        atomicAdd(&acc7[o], S);           atomicAdd(&acc7[256 + o], Q);
        atomicAdd(&acc7[512 + o], P);     atomicAdd(&acc7[768 + o], Y0);
        atomicAdd(&acc7[1024 + o], Q0);   atomicAdd(&acc7[1280 + o], Y63);
        atomicAdd(&acc7[1536 + o], Q63);
    }
}

// ------- K5: out = BN2(shift_out(y)) fp32, div-free masks. grid (64 n, 256 o) -------
__global__ __launch_bounds__(256) void k_bn2_apply(const unsigned short* __restrict__ y,
                                                   const float* __restrict__ theta,
                                                   const float* __restrict__ acc7,
                                                   const float* __restrict__ g,
                                                   const float* __restrict__ b,
                                                   float* __restrict__ out) {
    int o = blockIdx.y, n = blockIdx.x, tid = threadIdx.x;
    float th = theta[o];
    float fd = floorf(th);
    int d = (int)fd;
    float f = th - fd;
    float S = acc7[o], Q = acc7[256 + o], P = acc7[512 + o];
    float Y0 = acc7[768 + o], Q0 = acc7[1024 + o], Y63 = acc7[1280 + o], Q63 = acc7[1536 + o];
    float omf = 1.f - f;
    float sz, qz;
    if (d < 0) { sz = S - omf * Y63; qz = omf * omf * (Q - Q63) + f * f * Q + 2.f * f * omf * P; }
    else       { sz = S - f * Y0;    qz = omf * omf * Q + f * f * (Q - Q0) + 2.f * f * omf * P; }
    float mean = sz * Minv;
    float var = qz * Minv - mean * mean;
    float sc = g[o] * rsqrtf(var + EPSV);
    float tc = b[o] - mean * sc;
    if (tid >= 200) return;
    int e = tid * 8;
    const unsigned short* row = y + (size_t)n * CTV + (size_t)o * TV;
    float a0[8], a1[8];
    if (d < 0) {
        int eA = e - 32; if (eA < 0) eA = 0;
        int eB = e - 24; if (eB < 0) eB = 0;
        float A[8], B[8], M[8];
        unp8v(*(const uint4*)(row + eA), A);
        unp8v(*(const uint4*)(row + eB), B);
        unp8v(*(const uint4*)(row + e), M);
        a0[0] = (e >= 25) ? A[7] : 0.f;     // y[e-25]
#pragma unroll
        for (int k = 1; k < 8; ++k) a0[k] = (e + k >= 25) ? B[k - 1] : 0.f;
#pragma unroll
        for (int k = 0; k < 8; ++k) a1[k] = M[k];
    } else {
        int eB = e + 24; if (eB > 1592) eB = 1592;
        int eC = e + 32; if (eC > 1592) eC = 1592;
        float M[8], B[8], C[8];
        unp8v(*(const uint4*)(row + e), M);
        unp8v(*(const uint4*)(row + eB), B);
        unp8v(*(const uint4*)(row + eC), C);
#pragma unroll
        for (int k = 0; k < 8; ++k) a0[k] = M[k];
#pragma unroll
        for (int k = 0; k < 7; ++k) a1[k] = (e + k < 1575) ? B[k + 1] : 0.f;
        a1[7] = (e + 7 < 1575) ? C[0] : 0.f;
    }
    float4 r0, r1;
#pragma unroll
    for (int k = 0; k < 4; ++k) {
        ((float*)&r0)[k] = (omf * a0[k] + f * a1[k]) * sc + tc;
        ((float*)&r1)[k] = (omf * a0[k + 4] + f * a1[k + 4]) * sc + tc;
    }
    float* op = out + (size_t)n * CTV + (size_t)o * TV + e;
    *(float4*)op = r0;
    *(float4*)(op + 4) = r1;
}

extern "C" void kernel_launch(void* const* d_in, const int* in_sizes, int n_in,
                              void* d_out, int out_size, void* d_ws, size_t ws_size,
                              hipStream_t stream) {
    const float* x      = (const float*)d_in[0];
    const float* conv_w = (const float*)d_in[1];
    const float* conv_b = (const float*)d_in[2];
    const float* bn1_g  = (const float*)d_in[3];
    const float* bn1_b  = (const float*)d_in[4];
    const float* bn2_g  = (const float*)d_in[5];
    const float* bn2_b  = (const float*)d_in[6];
    const float* th_in  = (const float*)d_in[7];
    const float* th_out = (const float*)d_in[8];
    float* out = (float*)d_out;

    char* ws = (char*)d_ws;
    unsigned short* ht2 = (unsigned short*)ws;                  // 52,428,800 B  [c][j]
    unsigned short* yy = (unsigned short*)(ws + 52428800);      // 52,428,800 B
    unsigned short* wb = (unsigned short*)(ws + 104857600);     // 131,072 B
    float* sacc1 = (float*)(ws + 104988672);
    float* qacc1 = sacc1 + 256;
    float* acc7  = qacc1 + 256;          // 7*256
    float* b2all = acc7 + 7 * 256;
    float* s0v   = b2all + 256;
    float* s63v  = s0v + 256;

    hipMemsetAsync((void*)sacc1, 0, 9 * 256 * sizeof(float), stream);
    hipLaunchKernelGGL(k_bn1_stream, dim3(64, 256), dim3(256), 0, stream,
                       x, th_in, sacc1, qacc1, ht2);
    hipLaunchKernelGGL(k_params, dim3(256), dim3(256), 0, stream,
                       conv_w, conv_b, sacc1, qacc1, bn1_g, bn1_b, th_in,
                       wb, b2all, s0v, s63v);
    hipLaunchKernelGGL(k_gemm, dim3(800), dim3(256), 0, stream,
                       ht2, wb, b2all, s0v, s63v, yy);
    hipLaunchKernelGGL(k_bn2_stats, dim3(8, 256), dim3(256), 0, stream, yy, acc7);
    hipLaunchKernelGGL(k_bn2_apply, dim3(64, 256), dim3(256), 0, stream,
                       yy, th_out, acc7, bn2_g, bn2_b, out);
}